// Round 3
// baseline (380.325 us; speedup 1.0000x reference)
//
#include <hip/hip_runtime.h>

#define SEQ 2048
#define BATCH 32
#define HID 1024
#define SCHUNK 16

// Kernel 1: v[b,h] = sum_k hidden[b,k] * W[k,h]   (v = hidden @ W)
// Split-K: grid (b, hc) = (32, 8) = 256 blocks (one per CU).
__global__ void __launch_bounds__(256) vproj_kernel(const float* __restrict__ hidden,
                                                    const float* __restrict__ W,
                                                    float* __restrict__ v) {
    const int b  = blockIdx.x;
    const int hc = blockIdx.y;
    const int t  = threadIdx.x;
    const int h4 = hc * 32 + (t & 31);
    const int kk = t >> 5;

    __shared__ float  sh[HID];
    __shared__ float4 red[256];

    ((float4*)sh)[t] = ((const float4*)(hidden + b * HID))[t];
    __syncthreads();

    const float4* __restrict__ W4 = (const float4*)W;  // [HID][HID/4]
    float4 acc = make_float4(0.f, 0.f, 0.f, 0.f);
    const int k0 = kk * 128;
#pragma unroll 8
    for (int k = k0; k < k0 + 128; ++k) {
        const float  hk = sh[k];
        const float4 w  = W4[k * (HID / 4) + h4];
        acc.x = fmaf(hk, w.x, acc.x);
        acc.y = fmaf(hk, w.y, acc.y);
        acc.z = fmaf(hk, w.z, acc.z);
        acc.w = fmaf(hk, w.w, acc.w);
    }

    red[t] = acc;
    __syncthreads();
    if (t < 128) {
        float4 a = red[t], c = red[t + 128];
        a.x += c.x; a.y += c.y; a.z += c.z; a.w += c.w;
        red[t] = a;
    }
    __syncthreads();
    if (t < 64) {
        float4 a = red[t], c = red[t + 64];
        a.x += c.x; a.y += c.y; a.z += c.z; a.w += c.w;
        red[t] = a;
    }
    __syncthreads();
    if (t < 32) {
        float4 a = red[t], c = red[t + 32];
        a.x += c.x; a.y += c.y; a.z += c.z; a.w += c.w;
        ((float4*)v)[b * (HID / 4) + hc * 32 + t] = a;
    }
}

// Kernel 2: scores[b,s] = enc[s,b,:] . v[b,:]
// Block = 4 waves (b = by*4+wave) x SCHUNK s-values. v for the 4 b's staged
// once in LDS (16 KB). Each thread issues 4 independent enc float4 loads per
// s, SCHUNK s-values per block -> deep memory pipelining; shuffle reductions
// deferred to the end. Grid = (SEQ/SCHUNK, BATCH/4) = (128,8) = 1024 blocks.
__global__ void __launch_bounds__(256) score_kernel(const float* __restrict__ enc,
                                                    const float* __restrict__ v,
                                                    float* __restrict__ scores) {
    const int s0   = blockIdx.x * SCHUNK;
    const int wave = threadIdx.x >> 6;
    const int lane = threadIdx.x & 63;
    const int b    = blockIdx.y * 4 + wave;

    __shared__ float4 vsh[4 * 256];  // 16 KB: v rows for the 4 b's
    {
        const float4* __restrict__ v4 = (const float4*)(v + (size_t)blockIdx.y * 4 * HID);
#pragma unroll
        for (int i = 0; i < 4; ++i)
            vsh[i * 256 + threadIdx.x] = v4[i * 256 + threadIdx.x];
    }
    __syncthreads();

    const float4* __restrict__ e4b = (const float4*)enc;  // [S*B*256]
    float acc[SCHUNK];

#pragma unroll 4
    for (int i = 0; i < SCHUNK; ++i) {
        const float4* __restrict__ e4 = e4b + ((size_t)(s0 + i) * BATCH + b) * (HID / 4);
        float a = 0.f;
#pragma unroll
        for (int j = 0; j < 4; ++j) {
            const float4 e = e4[j * 64 + lane];            // coalesced 16B/lane
            const float4 w = vsh[wave * 256 + j * 64 + lane];
            a = fmaf(e.x, w.x, a);
            a = fmaf(e.y, w.y, a);
            a = fmaf(e.z, w.z, a);
            a = fmaf(e.w, w.w, a);
        }
        acc[i] = a;
    }

#pragma unroll
    for (int i = 0; i < SCHUNK; ++i) {
#pragma unroll
        for (int off = 32; off > 0; off >>= 1) acc[i] += __shfl_xor(acc[i], off, 64);
        if (lane == 0) scores[b * SEQ + s0 + i] = acc[i];
    }
}

// Kernel 3: out[b,s] = softmax_s(scores[b,:]). One block per b.
__global__ void __launch_bounds__(256) softmax_kernel(const float* __restrict__ scores,
                                                      float* __restrict__ out) {
    const int b = blockIdx.x;
    const int t = threadIdx.x;
    __shared__ float red[256];

    float x[8];
    float m = -INFINITY;
#pragma unroll
    for (int j = 0; j < 8; ++j) {
        x[j] = scores[b * SEQ + t + j * 256];
        m = fmaxf(m, x[j]);
    }
    red[t] = m;
    __syncthreads();
    for (int o = 128; o > 0; o >>= 1) {
        if (t < o) red[t] = fmaxf(red[t], red[t + o]);
        __syncthreads();
    }
    m = red[0];
    __syncthreads();

    float sum = 0.f;
#pragma unroll
    for (int j = 0; j < 8; ++j) {
        x[j] = __expf(x[j] - m);
        sum += x[j];
    }
    red[t] = sum;
    __syncthreads();
    for (int o = 128; o > 0; o >>= 1) {
        if (t < o) red[t] += red[t + o];
        __syncthreads();
    }
    const float inv = 1.f / red[0];
#pragma unroll
    for (int j = 0; j < 8; ++j) out[b * SEQ + t + j * 256] = x[j] * inv;
}

extern "C" void kernel_launch(void* const* d_in, const int* in_sizes, int n_in,
                              void* d_out, int out_size, void* d_ws, size_t ws_size,
                              hipStream_t stream) {
    const float* hidden = (const float*)d_in[0];  // [B,H]
    const float* enc    = (const float*)d_in[1];  // [S,B,H]
    const float* W      = (const float*)d_in[2];  // [H,H]
    // d_in[3] = bias: constant over s per b -> cancels in softmax; unused.
    float* out = (float*)d_out;                   // [1,B,S] fp32

    float* v      = (float*)d_ws;                 // B*H   floats (128 KB)
    float* scores = v + BATCH * HID;              // B*S   floats (256 KB)

    vproj_kernel<<<dim3(BATCH, 8), 256, 0, stream>>>(hidden, W, v);
    score_kernel<<<dim3(SEQ / SCHUNK, BATCH / 4), 256, 0, stream>>>(enc, v, scores);
    softmax_kernel<<<BATCH, 256, 0, stream>>>(scores, out);
}